// Round 1
// baseline (638.666 us; speedup 1.0000x reference)
//
#include <hip/hip_runtime.h>
#include <math.h>

// ----------------------------------------------------------------------------
// NL-means denoise (skimage slow-mode math) + db2-wavelet sigma estimate.
// Stage 1: wavelet HH conv (stride2, symmetric pad) -> |.| -> 16384-bin hist
// Stage 2: single-block hist scan -> per-channel median -> sigma -> var,1/h^2
// Stage 3: tiled NLM: per 64x32 tile, loop 169 offsets:
//          A: diff^2 (channel-sum) on 36x68 ext region -> LDS
//          B: horizontal 5-tap Gaussian conv (coeffs pre-scaled by 1/3) -> LDS
//          C: vertical 5-tap conv -> w=exp(-max(d-2s^2,0)/h^2) -> reg accum
// ----------------------------------------------------------------------------

#define IMG   1024
#define HH_N  514
#define NBINS 16384
#define BIN_SCALE 4096.0f

#define TW 64
#define TH 32
#define EXTW 68          // TW+4
#define EXTH 36          // TH+4
#define LROWS 48         // TH+16
#define LCOLS 80         // TW+16
#define PLANE (LROWS*LCOLS + 2)   // +2: even (8B align), shifts banks per plane

// Gaussian patch kernel, normalized separable taps gn = g/sum(g), g=exp(-u^2/2)
#define G0 0.05448868454910367f
#define G1 0.24420134203151178f
#define G2 0.40261994689466440f
// horizontal pass taps pre-multiplied by 1/3 (channel mean)
#define B0 0.01816289484970122f
#define B1 0.08140044734383726f
#define B2 0.13420664896488813f

#define MAD_INV 1.4826022185056018f   // 1/0.6744897501960817

// ---------------------------------------------------------------- stage 1
__global__ void wavelet_hist(const float* __restrict__ x, int* __restrict__ hist) {
    int idx = blockIdx.x * 256 + threadIdx.x;
    if (idx >= 3 * HH_N * HH_N) return;
    int c   = idx / (HH_N * HH_N);
    int rem = idx - c * (HH_N * HH_N);
    int i   = rem / HH_N;
    int j   = rem - i * HH_N;
    const float k4[4] = {-0.48296291314469025f, 0.8365163037378079f,
                         -0.2241438680420134f, -0.12940952255126037f};
    float acc = 0.f;
#pragma unroll
    for (int a = 0; a < 4; ++a) {
        int sy = 2 * i + a - 3;                       // 'symmetric' pad
        sy = sy < 0 ? -sy - 1 : (sy >= IMG ? 2 * IMG - 1 - sy : sy);
        float r = 0.f;
#pragma unroll
        for (int b = 0; b < 4; ++b) {
            int sx = 2 * j + b - 3;
            sx = sx < 0 ? -sx - 1 : (sx >= IMG ? 2 * IMG - 1 - sx : sx);
            r += k4[b] * x[(sy * IMG + sx) * 3 + c];
        }
        acc += k4[a] * r;
    }
    float v = fabsf(acc);
    int bin = (int)(v * BIN_SCALE);
    bin = bin > NBINS - 1 ? NBINS - 1 : bin;
    atomicAdd(&hist[c * NBINS + bin], 1);
}

// ---------------------------------------------------------------- stage 2
__global__ void sigma_scan(const int* __restrict__ hist, float* __restrict__ scal) {
    __shared__ int   sscan[1024];
    __shared__ float sres[4];   // [0]=a[k1] val, [1]=a[k2] val, [2]=sigma accum
    int t = threadIdx.x;
    for (int c = 0; c < 3; ++c) {
        const int* h = hist + c * NBINS;
        int base = t * 16;
        int s = 0;
#pragma unroll
        for (int b = 0; b < 16; ++b) s += h[base + b];
        sscan[t] = s;
        __syncthreads();
        for (int o = 1; o < 1024; o <<= 1) {            // inclusive scan
            int v = (t >= o) ? sscan[t - o] : 0;
            __syncthreads();
            sscan[t] += v;
            __syncthreads();
        }
        int cum = sscan[t] - s;                         // exclusive prefix
        // n=264196 even: median = (a[132097]+a[132098])/2 (0-based)
#pragma unroll
        for (int b = 0; b < 16; ++b) {
            int nc = cum + h[base + b];
            float v = (base + b + 0.5f) * (1.0f / BIN_SCALE);
            if (cum < 132098 && nc >= 132098) sres[0] = v;
            if (cum < 132099 && nc >= 132099) sres[1] = v;
            cum = nc;
        }
        __syncthreads();
        if (t == 0) {
            float med = 0.5f * (sres[0] + sres[1]);
            float prev = (c == 0) ? 0.f : sres[2];
            sres[2] = prev + med * MAD_INV;
        }
        __syncthreads();
    }
    if (t == 0) {
        float sigma = sres[2] * (1.0f / 3.0f);
        float hw = 0.8f * sigma;
        scal[0] = 2.0f * sigma * sigma;      // var
        scal[1] = 1.0f / (hw * hw);          // 1/h^2
    }
}

// ---------------------------------------------------------------- stage 3
__launch_bounds__(512, 4)
__global__ void nlm_main(const float* __restrict__ x,
                         const float* __restrict__ scal,
                         float* __restrict__ out) {
    __shared__ __align__(16) float sx[3 * PLANE];      // pixel tile, planar
    __shared__ __align__(16) float sd[EXTH * EXTW];    // diff^2 (ch-summed)
    __shared__ __align__(16) float sh[EXTH * TW];      // after horiz conv

    const int tid = threadIdx.x;
    const int X0 = blockIdx.x * TW;
    const int Y0 = blockIdx.y * TH;

    // --- load reflect-padded pixel tile (xp rows [Y0,Y0+48), cols [X0,X0+80))
    for (int l = tid; l < LROWS * LCOLS * 3; l += 512) {
        int rr  = l / (LCOLS * 3);
        int rem = l - rr * (LCOLS * 3);
        int cc  = rem / 3;
        int c   = rem - cc * 3;
        int sy = Y0 + rr - 8;                           // 'reflect' pad
        sy = sy < 0 ? -sy : (sy >= IMG ? 2 * IMG - 2 - sy : sy);
        int sc = X0 + cc - 8;
        sc = sc < 0 ? -sc : (sc >= IMG ? 2 * IMG - 2 - sc : sc);
        sx[c * PLANE + rr * LCOLS + cc] = x[(sy * IMG + sc) * 3 + c];
    }

    const float var = scal[0];
    const float ih2 = scal[1];

    const int lx = tid & 63;          // output col within tile
    const int yb = (tid >> 6) * 4;    // first of 4 output rows
    float a0x = 0, a0y = 0, a0z = 0, w0s = 0;
    float a1x = 0, a1y = 0, a1z = 0, w1s = 0;
    float a2x = 0, a2y = 0, a2z = 0, w2s = 0;
    float a3x = 0, a3y = 0, a3z = 0, w3s = 0;

    __syncthreads();

#pragma unroll 1
    for (int off = 0; off < 169; ++off) {
        const int oy = off / 13 - 6;
        const int ox = off - (off / 13) * 13 - 6;

        // -------- phase A: diff^2 over 36x68 ext region (vec4 tasks)
        for (int t = tid; t < EXTH * 17; t += 512) {
            int row = t / 17;
            int c4  = t - row * 17;
            int dx  = c4 * 4;
            int r1 = (row + 6) * LCOLS + dx + 6;
            int r2 = (row + 6 + oy) * LCOLS + dx + 6 + ox;
            float d0 = 0, d1 = 0, d2 = 0, d3 = 0;
#pragma unroll
            for (int c = 0; c < 3; ++c) {
                const float* p1 = &sx[c * PLANE + r1];
                const float* p2 = &sx[c * PLANE + r2];
                float e0 = p1[0] - p2[0];
                float e1 = p1[1] - p2[1];
                float e2 = p1[2] - p2[2];
                float e3 = p1[3] - p2[3];
                d0 += e0 * e0; d1 += e1 * e1; d2 += e2 * e2; d3 += e3 * e3;
            }
            *(float4*)&sd[row * EXTW + dx] = make_float4(d0, d1, d2, d3);
        }
        __syncthreads();

        // -------- phase B: horizontal conv (taps pre-scaled by 1/3)
        for (int t = tid; t < EXTH * 16; t += 512) {
            int row = t >> 4;
            int xb4 = (t & 15) * 4;
            float4 a = *(const float4*)&sd[row * EXTW + xb4];
            float4 b = *(const float4*)&sd[row * EXTW + xb4 + 4];
            float w0 = B0 * a.x + B1 * a.y + B2 * a.z + B1 * a.w + B0 * b.x;
            float w1 = B0 * a.y + B1 * a.z + B2 * a.w + B1 * b.x + B0 * b.y;
            float w2 = B0 * a.z + B1 * a.w + B2 * b.x + B1 * b.y + B0 * b.z;
            float w3 = B0 * a.w + B1 * b.x + B2 * b.y + B1 * b.z + B0 * b.w;
            *(float4*)&sh[row * TW + xb4] = make_float4(w0, w1, w2, w3);
        }
        __syncthreads();

        // -------- phase C: vertical conv + weight + accumulate (4 rows/thread)
        {
            float s0 = sh[(yb + 0) * TW + lx];
            float s1 = sh[(yb + 1) * TW + lx];
            float s2 = sh[(yb + 2) * TW + lx];
            float s3 = sh[(yb + 3) * TW + lx];
            float s4 = sh[(yb + 4) * TW + lx];
            float s5 = sh[(yb + 5) * TW + lx];
            float s6 = sh[(yb + 6) * TW + lx];
            float s7 = sh[(yb + 7) * TW + lx];
            float d0 = G0 * s0 + G1 * s1 + G2 * s2 + G1 * s3 + G0 * s4;
            float d1 = G0 * s1 + G1 * s2 + G2 * s3 + G1 * s4 + G0 * s5;
            float d2 = G0 * s2 + G1 * s3 + G2 * s4 + G1 * s5 + G0 * s6;
            float d3 = G0 * s3 + G1 * s4 + G2 * s5 + G1 * s6 + G0 * s7;
            float w0 = __expf(fminf(var - d0, 0.f) * ih2);
            float w1 = __expf(fminf(var - d1, 0.f) * ih2);
            float w2 = __expf(fminf(var - d2, 0.f) * ih2);
            float w3 = __expf(fminf(var - d3, 0.f) * ih2);
            int cb = (yb + 8 + oy) * LCOLS + (lx + 8 + ox);
            {
                const float* pc = &sx[0 * PLANE + cb];
                a0x += w0 * pc[0];         a1x += w1 * pc[LCOLS];
                a2x += w2 * pc[2 * LCOLS]; a3x += w3 * pc[3 * LCOLS];
            }
            {
                const float* pc = &sx[1 * PLANE + cb];
                a0y += w0 * pc[0];         a1y += w1 * pc[LCOLS];
                a2y += w2 * pc[2 * LCOLS]; a3y += w3 * pc[3 * LCOLS];
            }
            {
                const float* pc = &sx[2 * PLANE + cb];
                a0z += w0 * pc[0];         a1z += w1 * pc[LCOLS];
                a2z += w2 * pc[2 * LCOLS]; a3z += w3 * pc[3 * LCOLS];
            }
            w0s += w0; w1s += w1; w2s += w2; w3s += w3;
        }
        // no barrier needed: next A writes sd (readers done at bar after A->B),
        // next B writes sh only after the post-A barrier.
    }

    // -------- epilogue
    {
        int p0 = ((Y0 + yb + 0) * IMG + X0 + lx) * 3;
        int p1 = ((Y0 + yb + 1) * IMG + X0 + lx) * 3;
        int p2 = ((Y0 + yb + 2) * IMG + X0 + lx) * 3;
        int p3 = ((Y0 + yb + 3) * IMG + X0 + lx) * 3;
        float r0 = 1.f / w0s, r1 = 1.f / w1s, r2 = 1.f / w2s, r3 = 1.f / w3s;
        out[p0 + 0] = a0x * r0; out[p0 + 1] = a0y * r0; out[p0 + 2] = a0z * r0;
        out[p1 + 0] = a1x * r1; out[p1 + 1] = a1y * r1; out[p1 + 2] = a1z * r1;
        out[p2 + 0] = a2x * r2; out[p2 + 1] = a2y * r2; out[p2 + 2] = a2z * r2;
        out[p3 + 0] = a3x * r3; out[p3 + 1] = a3y * r3; out[p3 + 2] = a3z * r3;
    }
}

// ---------------------------------------------------------------- launch
extern "C" void kernel_launch(void* const* d_in, const int* in_sizes, int n_in,
                              void* d_out, int out_size, void* d_ws, size_t ws_size,
                              hipStream_t stream) {
    const float* x = (const float*)d_in[0];
    float* out = (float*)d_out;
    float* scal = (float*)d_ws;                       // [0]=var, [1]=1/h^2
    int* hist = (int*)((char*)d_ws + 64);             // 3*16384 ints

    hipMemsetAsync(hist, 0, 3 * NBINS * sizeof(int), stream);
    wavelet_hist<<<(3 * HH_N * HH_N + 255) / 256, 256, 0, stream>>>(x, hist);
    sigma_scan<<<1, 1024, 0, stream>>>(hist, scal);
    dim3 grid(IMG / TW, IMG / TH);
    nlm_main<<<grid, 512, 0, stream>>>(x, scal, out);
}

// Round 2
// 454.457 us; speedup vs baseline: 1.4053x; 1.4053x over previous
//
#include <hip/hip_runtime.h>
#include <math.h>

// ----------------------------------------------------------------------------
// NL-means denoise (skimage slow-mode math) + db2-wavelet sigma estimate.
// Stage 1: wavelet HH conv (stride2, symmetric pad) -> |.| -> 16384-bin hist
// Stage 2: single-block hist scan -> per-channel median -> sigma -> var,1/h^2
// Stage 3: tiled NLM: per 64x32 tile, loop 169 offsets:
//          A: diff^2 (channel-sum) on 36x68 ext region -> LDS
//             [R2: lane-stride-1, center region register-cached — kills the
//              1.35e8 bank-conflict cycles of R1's stride-16B phase A]
//          B: horizontal 5-tap Gaussian conv (coeffs pre-scaled by 1/3) -> LDS
//          C: vertical 5-tap conv -> w=exp(-max(d-2s^2,0)/h^2) -> reg accum
// ----------------------------------------------------------------------------

#define IMG   1024
#define HH_N  514
#define NBINS 16384
#define BIN_SCALE 4096.0f

#define TW 64
#define TH 32
#define EXTW 68          // TW+4
#define EXTH 36          // TH+4
#define NEXT (EXTH*EXTW) // 2448 diff^2 outputs
#define LROWS 48         // TH+16
#define LCOLS 80         // TW+16
#define PLANE (LROWS*LCOLS + 2)   // +2: even (8B align), shifts banks per plane

// Gaussian patch kernel, normalized separable taps gn = g/sum(g), g=exp(-u^2/2)
#define G0 0.05448868454910367f
#define G1 0.24420134203151178f
#define G2 0.40261994689466440f
// horizontal pass taps pre-multiplied by 1/3 (channel mean)
#define B0 0.01816289484970122f
#define B1 0.08140044734383726f
#define B2 0.13420664896488813f

#define MAD_INV 1.4826022185056018f   // 1/0.6744897501960817

// ---------------------------------------------------------------- stage 1
__global__ void wavelet_hist(const float* __restrict__ x, int* __restrict__ hist) {
    int idx = blockIdx.x * 256 + threadIdx.x;
    if (idx >= 3 * HH_N * HH_N) return;
    int c   = idx / (HH_N * HH_N);
    int rem = idx - c * (HH_N * HH_N);
    int i   = rem / HH_N;
    int j   = rem - i * HH_N;
    const float k4[4] = {-0.48296291314469025f, 0.8365163037378079f,
                         -0.2241438680420134f, -0.12940952255126037f};
    float acc = 0.f;
#pragma unroll
    for (int a = 0; a < 4; ++a) {
        int sy = 2 * i + a - 3;                       // 'symmetric' pad
        sy = sy < 0 ? -sy - 1 : (sy >= IMG ? 2 * IMG - 1 - sy : sy);
        float r = 0.f;
#pragma unroll
        for (int b = 0; b < 4; ++b) {
            int sx = 2 * j + b - 3;
            sx = sx < 0 ? -sx - 1 : (sx >= IMG ? 2 * IMG - 1 - sx : sx);
            r += k4[b] * x[(sy * IMG + sx) * 3 + c];
        }
        acc += k4[a] * r;
    }
    float v = fabsf(acc);
    int bin = (int)(v * BIN_SCALE);
    bin = bin > NBINS - 1 ? NBINS - 1 : bin;
    atomicAdd(&hist[c * NBINS + bin], 1);
}

// ---------------------------------------------------------------- stage 2
__global__ void sigma_scan(const int* __restrict__ hist, float* __restrict__ scal) {
    __shared__ int   sscan[1024];
    __shared__ float sres[4];   // [0]=a[k1] val, [1]=a[k2] val, [2]=sigma accum
    int t = threadIdx.x;
    for (int c = 0; c < 3; ++c) {
        const int* h = hist + c * NBINS;
        int base = t * 16;
        int s = 0;
#pragma unroll
        for (int b = 0; b < 16; ++b) s += h[base + b];
        sscan[t] = s;
        __syncthreads();
        for (int o = 1; o < 1024; o <<= 1) {            // inclusive scan
            int v = (t >= o) ? sscan[t - o] : 0;
            __syncthreads();
            sscan[t] += v;
            __syncthreads();
        }
        int cum = sscan[t] - s;                         // exclusive prefix
        // n=264196 even: median = (a[132097]+a[132098])/2 (0-based)
#pragma unroll
        for (int b = 0; b < 16; ++b) {
            int nc = cum + h[base + b];
            float v = (base + b + 0.5f) * (1.0f / BIN_SCALE);
            if (cum < 132098 && nc >= 132098) sres[0] = v;
            if (cum < 132099 && nc >= 132099) sres[1] = v;
            cum = nc;
        }
        __syncthreads();
        if (t == 0) {
            float med = 0.5f * (sres[0] + sres[1]);
            float prev = (c == 0) ? 0.f : sres[2];
            sres[2] = prev + med * MAD_INV;
        }
        __syncthreads();
    }
    if (t == 0) {
        float sigma = sres[2] * (1.0f / 3.0f);
        float hw = 0.8f * sigma;
        scal[0] = 2.0f * sigma * sigma;      // var
        scal[1] = 1.0f / (hw * hw);          // 1/h^2
    }
}

// ---------------------------------------------------------------- stage 3
__launch_bounds__(512, 4)
__global__ void nlm_main(const float* __restrict__ x,
                         const float* __restrict__ scal,
                         float* __restrict__ out) {
    __shared__ __align__(16) float sx[3 * PLANE];      // pixel tile, planar
    __shared__ __align__(16) float sd[NEXT];           // diff^2 (ch-summed)
    __shared__ __align__(16) float sh[EXTH * TW];      // after horiz conv

    const int tid = threadIdx.x;
    const int X0 = blockIdx.x * TW;
    const int Y0 = blockIdx.y * TH;

    // --- load reflect-padded pixel tile (xp rows [Y0,Y0+48), cols [X0,X0+80))
    for (int l = tid; l < LROWS * LCOLS * 3; l += 512) {
        int rr  = l / (LCOLS * 3);
        int rem = l - rr * (LCOLS * 3);
        int cc  = rem / 3;
        int c   = rem - cc * 3;
        int sy = Y0 + rr - 8;                           // 'reflect' pad
        sy = sy < 0 ? -sy : (sy >= IMG ? 2 * IMG - 2 - sy : sy);
        int sc = X0 + cc - 8;
        sc = sc < 0 ? -sc : (sc >= IMG ? 2 * IMG - 2 - sc : sc);
        sx[c * PLANE + rr * LCOLS + cc] = x[(sy * IMG + sc) * 3 + c];
    }

    const float var = scal[0];
    const float ih2 = scal[1];

    const int lx = tid & 63;          // output col within tile
    const int yb = (tid >> 6) * 4;    // first of 4 output rows
    float a0x = 0, a0y = 0, a0z = 0, w0s = 0;
    float a1x = 0, a1y = 0, a1z = 0, w1s = 0;
    float a2x = 0, a2y = 0, a2z = 0, w2s = 0;
    float a3x = 0, a3y = 0, a3z = 0, w3s = 0;

    __syncthreads();

    // --- register-cache the offset-invariant center region for phase A
    // thread t owns diff^2 outputs {t, t+512, t+1024, t+1536, t+2048}
    float p1c0[5], p1c1[5], p1c2[5];
    int   rb[5];
#pragma unroll
    for (int k = 0; k < 5; ++k) {
        int o = tid + k * 512;
        if (o < NEXT) {
            int row = o / EXTW;
            int col = o - row * EXTW;
            int r1  = (row + 6) * LCOLS + col + 6;
            rb[k]   = r1;
            p1c0[k] = sx[0 * PLANE + r1];
            p1c1[k] = sx[1 * PLANE + r1];
            p1c2[k] = sx[2 * PLANE + r1];
        } else {
            rb[k] = 0; p1c0[k] = 0; p1c1[k] = 0; p1c2[k] = 0;
        }
    }

#pragma unroll 1
    for (int off = 0; off < 169; ++off) {
        const int oy = off / 13 - 6;
        const int ox = off - (off / 13) * 13 - 6;
        const int doff = oy * LCOLS + ox;

        // -------- phase A: diff^2, one output/thread, lane-stride-1 reads
#pragma unroll
        for (int k = 0; k < 5; ++k) {
            int o = tid + k * 512;
            if (k < 4 || o < NEXT) {
                int r2 = rb[k] + doff;
                float e0 = p1c0[k] - sx[0 * PLANE + r2];
                float e1 = p1c1[k] - sx[1 * PLANE + r2];
                float e2 = p1c2[k] - sx[2 * PLANE + r2];
                sd[o] = e0 * e0 + e1 * e1 + e2 * e2;
            }
        }
        __syncthreads();

        // -------- phase B: horizontal conv (taps pre-scaled by 1/3)
        for (int t = tid; t < EXTH * 16; t += 512) {
            int row = t >> 4;
            int xb4 = (t & 15) * 4;
            float4 a = *(const float4*)&sd[row * EXTW + xb4];
            float4 b = *(const float4*)&sd[row * EXTW + xb4 + 4];
            float w0 = B0 * a.x + B1 * a.y + B2 * a.z + B1 * a.w + B0 * b.x;
            float w1 = B0 * a.y + B1 * a.z + B2 * a.w + B1 * b.x + B0 * b.y;
            float w2 = B0 * a.z + B1 * a.w + B2 * b.x + B1 * b.y + B0 * b.z;
            float w3 = B0 * a.w + B1 * b.x + B2 * b.y + B1 * b.z + B0 * b.w;
            *(float4*)&sh[row * TW + xb4] = make_float4(w0, w1, w2, w3);
        }
        __syncthreads();

        // -------- phase C: vertical conv + weight + accumulate (4 rows/thread)
        {
            float s0 = sh[(yb + 0) * TW + lx];
            float s1 = sh[(yb + 1) * TW + lx];
            float s2 = sh[(yb + 2) * TW + lx];
            float s3 = sh[(yb + 3) * TW + lx];
            float s4 = sh[(yb + 4) * TW + lx];
            float s5 = sh[(yb + 5) * TW + lx];
            float s6 = sh[(yb + 6) * TW + lx];
            float s7 = sh[(yb + 7) * TW + lx];
            float d0 = G0 * s0 + G1 * s1 + G2 * s2 + G1 * s3 + G0 * s4;
            float d1 = G0 * s1 + G1 * s2 + G2 * s3 + G1 * s4 + G0 * s5;
            float d2 = G0 * s2 + G1 * s3 + G2 * s4 + G1 * s5 + G0 * s6;
            float d3 = G0 * s3 + G1 * s4 + G2 * s5 + G1 * s6 + G0 * s7;
            float w0 = __expf(fminf(var - d0, 0.f) * ih2);
            float w1 = __expf(fminf(var - d1, 0.f) * ih2);
            float w2 = __expf(fminf(var - d2, 0.f) * ih2);
            float w3 = __expf(fminf(var - d3, 0.f) * ih2);
            int cb = (yb + 8 + oy) * LCOLS + (lx + 8 + ox);
            {
                const float* pc = &sx[0 * PLANE + cb];
                a0x += w0 * pc[0];         a1x += w1 * pc[LCOLS];
                a2x += w2 * pc[2 * LCOLS]; a3x += w3 * pc[3 * LCOLS];
            }
            {
                const float* pc = &sx[1 * PLANE + cb];
                a0y += w0 * pc[0];         a1y += w1 * pc[LCOLS];
                a2y += w2 * pc[2 * LCOLS]; a3y += w3 * pc[3 * LCOLS];
            }
            {
                const float* pc = &sx[2 * PLANE + cb];
                a0z += w0 * pc[0];         a1z += w1 * pc[LCOLS];
                a2z += w2 * pc[2 * LCOLS]; a3z += w3 * pc[3 * LCOLS];
            }
            w0s += w0; w1s += w1; w2s += w2; w3s += w3;
        }
        // no barrier needed: next A writes sd (readers done at bar after A->B),
        // next B writes sh only after the post-A barrier.
    }

    // -------- epilogue
    {
        int p0 = ((Y0 + yb + 0) * IMG + X0 + lx) * 3;
        int p1 = ((Y0 + yb + 1) * IMG + X0 + lx) * 3;
        int p2 = ((Y0 + yb + 2) * IMG + X0 + lx) * 3;
        int p3 = ((Y0 + yb + 3) * IMG + X0 + lx) * 3;
        float r0 = 1.f / w0s, r1 = 1.f / w1s, r2 = 1.f / w2s, r3 = 1.f / w3s;
        out[p0 + 0] = a0x * r0; out[p0 + 1] = a0y * r0; out[p0 + 2] = a0z * r0;
        out[p1 + 0] = a1x * r1; out[p1 + 1] = a1y * r1; out[p1 + 2] = a1z * r1;
        out[p2 + 0] = a2x * r2; out[p2 + 1] = a2y * r2; out[p2 + 2] = a2z * r2;
        out[p3 + 0] = a3x * r3; out[p3 + 1] = a3y * r3; out[p3 + 2] = a3z * r3;
    }
}

// ---------------------------------------------------------------- launch
extern "C" void kernel_launch(void* const* d_in, const int* in_sizes, int n_in,
                              void* d_out, int out_size, void* d_ws, size_t ws_size,
                              hipStream_t stream) {
    const float* x = (const float*)d_in[0];
    float* out = (float*)d_out;
    float* scal = (float*)d_ws;                       // [0]=var, [1]=1/h^2
    int* hist = (int*)((char*)d_ws + 64);             // 3*16384 ints

    hipMemsetAsync(hist, 0, 3 * NBINS * sizeof(int), stream);
    wavelet_hist<<<(3 * HH_N * HH_N + 255) / 256, 256, 0, stream>>>(x, hist);
    sigma_scan<<<1, 1024, 0, stream>>>(hist, scal);
    dim3 grid(IMG / TW, IMG / TH);
    nlm_main<<<grid, 512, 0, stream>>>(x, scal, out);
}